// Round 1
// baseline (624.067 us; speedup 1.0000x reference)
//
#include <hip/hip_runtime.h>
#include <math.h>

#define LL    4096
#define CDIM  96
#define DIN   192
#define NST   16
#define XE    38   // dt_rank(6) + 2*16

// ---------------- Kernel 1: merge proj(1x1) into dconv(3x3) -> Wm[96][96][9]
__global__ __launch_bounds__(256) void k_merge_w(const float* __restrict__ proj_w,
                                                 const float* __restrict__ dconv_w,
                                                 float* __restrict__ Wm) {
    int idx = blockIdx.x * 256 + threadIdx.x;       // o*96*9 + c*9 + k
    if (idx >= 96 * 96 * 9) return;
    int k = idx % 9;
    int c = (idx / 9) % 96;
    int o = idx / (9 * 96);
    float s = 0.f;
    for (int i = 0; i < 192; ++i)
        s += dconv_w[(o * 192 + i) * 9 + k] * proj_w[i * 96 + c];
    Wm[idx] = s;
}

// ---------------- Kernel 2: 3x3 conv (96 -> 96), pad 1. out = seq (B,96,L)
#define CONV_CO 6
#define CIB 8
__global__ __launch_bounds__(256) void k_conv3x3(const float* __restrict__ x,
                                                 const float* __restrict__ Wm,
                                                 float* __restrict__ seq) {
    __shared__ float lin[CIB][18][35];  // 32x16 tile + halo, col padded to 35
    int tid = threadIdx.x;
    int tx = tid & 15, ty = tid >> 4;   // tx: x-pair 0..15, ty: row 0..15
    int sid = blockIdx.x;               // 0..7
    int x0 = (sid & 1) * 32, y0 = (sid >> 1) * 16;
    int co0 = blockIdx.y * CONV_CO;
    int b = blockIdx.z;
    const float* xb = x + b * 96 * LL;

    float acc[CONV_CO][2];
#pragma unroll
    for (int o = 0; o < CONV_CO; ++o) { acc[o][0] = 0.f; acc[o][1] = 0.f; }

    for (int cb = 0; cb < 96; cb += CIB) {
        for (int i = tid; i < CIB * 18 * 34; i += 256) {
            int col = i % 34;
            int row = (i / 34) % 18;
            int ci  = i / (34 * 18);
            int gx = x0 + col - 1, gy = y0 + row - 1;
            float v = 0.f;
            if (gx >= 0 && gx < 64 && gy >= 0 && gy < 64)
                v = xb[(cb + ci) * LL + gy * 64 + gx];
            lin[ci][row][col] = v;
        }
        __syncthreads();
#pragma unroll
        for (int ci = 0; ci < CIB; ++ci) {
            float iv[3][4];
#pragma unroll
            for (int r = 0; r < 3; ++r)
#pragma unroll
                for (int c2 = 0; c2 < 4; ++c2)
                    iv[r][c2] = lin[ci][ty + r][tx * 2 + c2];
            const float* wp = Wm + (co0 * 96 + cb + ci) * 9;
#pragma unroll
            for (int o = 0; o < CONV_CO; ++o) {
                const float* w9 = wp + o * 96 * 9;
#pragma unroll
                for (int r = 0; r < 3; ++r)
#pragma unroll
                    for (int kx = 0; kx < 3; ++kx) {
                        float wv = w9[r * 3 + kx];
                        acc[o][0] = fmaf(wv, iv[r][kx],     acc[o][0]);
                        acc[o][1] = fmaf(wv, iv[r][kx + 1], acc[o][1]);
                    }
            }
        }
        __syncthreads();
    }
    int gy = y0 + ty, gx = x0 + tx * 2;
#pragma unroll
    for (int o = 0; o < CONV_CO; ++o) {
        float2 v; v.x = acc[o][0]; v.y = acc[o][1];
        *(float2*)&seq[(b * 96 + co0 + o) * LL + gy * 64 + gx] = v;
    }
}

// ---------------- Generic channel-major GEMM: out[b][e][l] = sum_c W[e][c]*in[b][c][l]
template <int K, int EPER>
__global__ __launch_bounds__(256) void k_gemm(const float* __restrict__ in,
                                              const float* __restrict__ w,
                                              float* __restrict__ out,
                                              int inbs, int outbs) {
    int tx = threadIdx.x;                 // 64
    int ty = threadIdx.y;                 // 4
    int b = blockIdx.z;
    int l = blockIdx.x * 256 + tx * 4;
    int e0 = blockIdx.y * (EPER * 4) + ty * EPER;
    const float* inb = in + b * inbs + l;
    float acc[EPER][4];
#pragma unroll
    for (int j = 0; j < EPER; ++j)
        acc[j][0] = acc[j][1] = acc[j][2] = acc[j][3] = 0.f;

    for (int c = 0; c < K; ++c) {
        float4 v = *(const float4*)(inb + c * LL);
#pragma unroll
        for (int j = 0; j < EPER; ++j) {
            float wv = w[(e0 + j) * K + c];
            acc[j][0] = fmaf(wv, v.x, acc[j][0]);
            acc[j][1] = fmaf(wv, v.y, acc[j][1]);
            acc[j][2] = fmaf(wv, v.z, acc[j][2]);
            acc[j][3] = fmaf(wv, v.w, acc[j][3]);
        }
    }
#pragma unroll
    for (int j = 0; j < EPER; ++j) {
        float4 v; v.x = acc[j][0]; v.y = acc[j][1]; v.z = acc[j][2]; v.w = acc[j][3];
        *(float4*)(out + b * outbs + (e0 + j) * LL + l) = v;
    }
}

// ---------------- Kernel 4: causal depthwise conv1d (k=4) + SiLU
__global__ __launch_bounds__(256) void k_conv1d(const float* __restrict__ xz,
                                                const float* __restrict__ w,
                                                const float* __restrict__ bias,
                                                float* __restrict__ xc) {
    int tid = blockIdx.x * 256 + threadIdx.x;   // B*192*1024 threads
    int tq = tid & 1023;
    int bd = tid >> 10;
    int d = bd % DIN, b = bd / DIN;
    const float* xin = xz + (b * 384 + d) * LL;
    int t0 = tq * 4;
    float4 cur = *(const float4*)(xin + t0);
    float pm3 = 0.f, pm2 = 0.f, pm1 = 0.f;
    if (t0 > 0) {
        float4 prev = *(const float4*)(xin + t0 - 4);
        pm3 = prev.y; pm2 = prev.z; pm1 = prev.w;
    }
    float in[7] = {pm3, pm2, pm1, cur.x, cur.y, cur.z, cur.w};
    float w0 = w[d * 4 + 0], w1 = w[d * 4 + 1], w2 = w[d * 4 + 2], w3 = w[d * 4 + 3];
    float bb = bias[d];
    float o[4];
#pragma unroll
    for (int i = 0; i < 4; ++i) {
        float s = bb + w0 * in[i] + w1 * in[i + 1] + w2 * in[i + 2] + w3 * in[i + 3];
        o[i] = s / (1.f + expf(-s));
    }
    float4 ov; ov.x = o[0]; ov.y = o[1]; ov.z = o[2]; ov.w = o[3];
    *(float4*)(xc + (b * DIN + d) * LL + t0) = ov;
}

// ---------------- Kernel 5: x_proj -> x_dbl (B,L,38)
__global__ __launch_bounds__(256) void k_xproj(const float* __restrict__ xc,
                                               const float* __restrict__ xpw,
                                               float* __restrict__ xdbl) {
    int tx = threadIdx.x;           // 64
    int ty = threadIdx.y;           // 4
    int b = blockIdx.z;
    int l = blockIdx.x * 128 + tx * 2;
    int e0 = ty * 10;
    const float* inb = xc + b * DIN * LL + l;
    float acc[10][2];
#pragma unroll
    for (int j = 0; j < 10; ++j) { acc[j][0] = 0.f; acc[j][1] = 0.f; }
    for (int c = 0; c < DIN; ++c) {
        float2 v = *(const float2*)(inb + c * LL);
#pragma unroll
        for (int j = 0; j < 10; ++j) {
            int e = e0 + j; if (e > 37) e = 37;      // clamp (garbage acc unused)
            float wv = xpw[e * DIN + c];
            acc[j][0] = fmaf(wv, v.x, acc[j][0]);
            acc[j][1] = fmaf(wv, v.y, acc[j][1]);
        }
    }
#pragma unroll
    for (int j = 0; j < 10; ++j) {
        int e = e0 + j;
        if (e < XE) {
            xdbl[(b * LL + l) * XE + e]     = acc[j][0];
            xdbl[(b * LL + l + 1) * XE + e] = acc[j][1];
        }
    }
}

// ---------------- Kernel 6: dt_proj + softplus -> delta (B,192,L)
__global__ __launch_bounds__(256) void k_dtproj(const float* __restrict__ xdbl,
                                                const float* __restrict__ dtw,
                                                const float* __restrict__ dtb,
                                                float* __restrict__ delta) {
    int tx = threadIdx.x;       // 64
    int ty = threadIdx.y;       // 4
    int b = blockIdx.y;
    int l = blockIdx.x * 64 + tx;
    const float* dtr = xdbl + (b * LL + l) * XE;
    float r0 = dtr[0], r1 = dtr[1], r2 = dtr[2], r3 = dtr[3], r4 = dtr[4], r5 = dtr[5];
    for (int dd = ty * 48; dd < ty * 48 + 48; ++dd) {
        const float* wr = dtw + dd * 6;
        float s = dtb[dd] + wr[0] * r0 + wr[1] * r1 + wr[2] * r2
                          + wr[3] * r3 + wr[4] * r4 + wr[5] * r5;
        float sp = (s > 20.f) ? s : log1pf(expf(s));
        delta[(b * DIN + dd) * LL + l] = sp;
    }
}

// ---------------- Kernel 7: chunked selective scan + gate. yg overwrites xz ch 0..191
__global__ __launch_bounds__(256) void k_scan(const float* __restrict__ delta,
                                              const float* __restrict__ xc,
                                              const float* __restrict__ xdbl,
                                              const float* __restrict__ A_log,
                                              const float* __restrict__ Dp,
                                              float* __restrict__ xz) {
    __shared__ float s_aP[16][16];
    __shared__ float s_h[16][16];
    int tid = threadIdx.x;
    int n = tid & 15, cg = tid >> 4;         // 16 chunks x 16 states
    int bd = blockIdx.x;
    int d = bd % DIN, b = bd / DIN;
    const float* drow = delta + (size_t)(b * DIN + d) * LL;
    const float* urow = xc + (size_t)(b * DIN + d) * LL;
    const float* zrow = xz + (size_t)(b * 384 + DIN + d) * LL;
    float* yrow = xz + (size_t)(b * 384 + d) * LL;
    const float* xd = xdbl + (size_t)b * LL * XE;
    float A2 = -expf(A_log[d * NST + n]) * 1.44269504f;   // for exp2f
    float Dd = Dp[d];
    int t0 = cg * 256;

    // phase 1: per-chunk (prod dA, h from 0)
    float h = 0.f, aP = 1.f;
#pragma unroll 4
    for (int i = 0; i < 256; ++i) {
        int t = t0 + i;
        float du = drow[t];
        float u  = urow[t];
        float Bv = xd[t * XE + 6 + n];
        float dA = exp2f(du * A2);
        h  = dA * h + (du * u) * Bv;
        aP *= dA;
    }
    s_aP[cg][n] = aP;
    s_h[cg][n]  = h;
    __syncthreads();

    // phase 2: scan chunk aggregates (16 lanes), write h0 into s_aP
    if (tid < 16) {
        float hrun = 0.f;
        for (int c = 0; c < 16; ++c) {
            float a = s_aP[c][tid], hc = s_h[c][tid];
            s_aP[c][tid] = hrun;
            hrun = a * hrun + hc;
        }
    }
    __syncthreads();

    // phase 3: recompute with correct h0, reduce over n, gate, store
    h = s_aP[cg][n];
#pragma unroll 2
    for (int i = 0; i < 256; ++i) {
        int t = t0 + i;
        float du = drow[t];
        float u  = urow[t];
        float Bv = xd[t * XE + 6 + n];
        float Cv = xd[t * XE + 22 + n];
        float dA = exp2f(du * A2);
        h = dA * h + (du * u) * Bv;
        float p = h * Cv;
        p += __shfl_xor(p, 1);
        p += __shfl_xor(p, 2);
        p += __shfl_xor(p, 4);
        p += __shfl_xor(p, 8);
        float y = p + Dd * u;
        float z = zrow[t];
        float g = z / (1.f + expf(-z));
        if (n == 0) yrow[t] = y * g;
    }
}

extern "C" void kernel_launch(void* const* d_in, const int* in_sizes, int n_in,
                              void* d_out, int out_size, void* d_ws, size_t ws_size,
                              hipStream_t stream) {
    const float* x         = (const float*)d_in[0];
    const float* proj_w    = (const float*)d_in[1];
    const float* dconv_w   = (const float*)d_in[2];
    const float* in_proj_w = (const float*)d_in[3];
    const float* conv1d_w  = (const float*)d_in[4];
    const float* conv1d_b  = (const float*)d_in[5];
    const float* x_proj_w  = (const float*)d_in[6];
    const float* dt_proj_w = (const float*)d_in[7];
    const float* dt_proj_b = (const float*)d_in[8];
    const float* A_log     = (const float*)d_in[9];
    const float* Dp        = (const float*)d_in[10];
    const float* out_proj_w= (const float*)d_in[11];
    float* out = (float*)d_out;
    float* ws  = (float*)d_ws;

    float* Wm   = ws;                    // 82,944
    float* seq  = Wm + 82944;            // 4*96*4096   = 1,572,864
    float* xz   = seq + 1572864;         // 4*384*4096  = 6,291,456 (xin 0..191 -> later yg; z 192..383)
    float* xc   = xz + 6291456;          // 4*192*4096  = 3,145,728
    float* xdbl = xc + 3145728;          // 4*4096*38   =   622,592
    float* delta= xdbl + 622592;         // 4*192*4096  = 3,145,728

    k_merge_w<<<dim3(324), dim3(256), 0, stream>>>(proj_w, dconv_w, Wm);
    k_conv3x3<<<dim3(8, 16, 4), dim3(256), 0, stream>>>(x, Wm, seq);
    k_gemm<96, 16><<<dim3(16, 6, 4), dim3(64, 4), 0, stream>>>(seq, in_proj_w, xz,
                                                               96 * LL, 384 * LL);
    k_conv1d<<<dim3(3072), dim3(256), 0, stream>>>(xz, conv1d_w, conv1d_b, xc);
    k_xproj<<<dim3(32, 1, 4), dim3(64, 4), 0, stream>>>(xc, x_proj_w, xdbl);
    k_dtproj<<<dim3(64, 4), dim3(64, 4), 0, stream>>>(xdbl, dt_proj_w, dt_proj_b, delta);
    k_scan<<<dim3(768), dim3(256), 0, stream>>>(delta, xc, xdbl, A_log, Dp, xz);
    k_gemm<192, 12><<<dim3(16, 2, 4), dim3(64, 4), 0, stream>>>(xz, out_proj_w, out,
                                                                384 * LL, 96 * LL);
}

// Round 2
// 331.168 us; speedup vs baseline: 1.8844x; 1.8844x over previous
//
#include <hip/hip_runtime.h>
#include <math.h>

#define LL    4096
#define CDIM  96
#define DIN   192
#define NST   16
#define XE    38   // dt_rank(6) + 2*16

__device__ __forceinline__ float siluf(float x) {
    return x * __builtin_amdgcn_rcpf(1.f + __expf(-x));
}

// ---------------- Kernel 1: merge proj(1x1) into dconv(3x3) -> Wm[96][96][9]
__global__ __launch_bounds__(256) void k_merge_w(const float* __restrict__ proj_w,
                                                 const float* __restrict__ dconv_w,
                                                 float* __restrict__ Wm) {
    int idx = blockIdx.x * 256 + threadIdx.x;       // o*96*9 + c*9 + k
    if (idx >= 96 * 96 * 9) return;
    int k = idx % 9;
    int c = (idx / 9) % 96;
    int o = idx / (9 * 96);
    float s = 0.f;
    for (int i = 0; i < 192; ++i)
        s += dconv_w[(o * 192 + i) * 9 + k] * proj_w[i * 96 + c];
    Wm[idx] = s;
}

// ---------------- Kernel 2: 3x3 conv (96 -> 96), pad 1. out = seq (B,96,L)
#define CONV_CO 6
#define CIB 8
__global__ __launch_bounds__(256) void k_conv3x3(const float* __restrict__ x,
                                                 const float* __restrict__ Wm,
                                                 float* __restrict__ seq) {
    __shared__ float lin[CIB][18][35];  // 32x16 tile + halo, col padded to 35
    int tid = threadIdx.x;
    int tx = tid & 15, ty = tid >> 4;   // tx: x-pair 0..15, ty: row 0..15
    int sid = blockIdx.x;               // 0..7
    int x0 = (sid & 1) * 32, y0 = (sid >> 1) * 16;
    int co0 = blockIdx.y * CONV_CO;
    int b = blockIdx.z;
    const float* xb = x + b * 96 * LL;

    float acc[CONV_CO][2];
#pragma unroll
    for (int o = 0; o < CONV_CO; ++o) { acc[o][0] = 0.f; acc[o][1] = 0.f; }

    for (int cb = 0; cb < 96; cb += CIB) {
        for (int i = tid; i < CIB * 18 * 34; i += 256) {
            int col = i % 34;
            int row = (i / 34) % 18;
            int ci  = i / (34 * 18);
            int gx = x0 + col - 1, gy = y0 + row - 1;
            float v = 0.f;
            if (gx >= 0 && gx < 64 && gy >= 0 && gy < 64)
                v = xb[(cb + ci) * LL + gy * 64 + gx];
            lin[ci][row][col] = v;
        }
        __syncthreads();
#pragma unroll
        for (int ci = 0; ci < CIB; ++ci) {
            float iv[3][4];
#pragma unroll
            for (int r = 0; r < 3; ++r)
#pragma unroll
                for (int c2 = 0; c2 < 4; ++c2)
                    iv[r][c2] = lin[ci][ty + r][tx * 2 + c2];
            const float* wp = Wm + (co0 * 96 + cb + ci) * 9;
#pragma unroll
            for (int o = 0; o < CONV_CO; ++o) {
                const float* w9 = wp + o * 96 * 9;
#pragma unroll
                for (int r = 0; r < 3; ++r)
#pragma unroll
                    for (int kx = 0; kx < 3; ++kx) {
                        float wv = w9[r * 3 + kx];
                        acc[o][0] = fmaf(wv, iv[r][kx],     acc[o][0]);
                        acc[o][1] = fmaf(wv, iv[r][kx + 1], acc[o][1]);
                    }
            }
        }
        __syncthreads();
    }
    int gy = y0 + ty, gx = x0 + tx * 2;
#pragma unroll
    for (int o = 0; o < CONV_CO; ++o) {
        float2 v; v.x = acc[o][0]; v.y = acc[o][1];
        *(float2*)&seq[(b * 96 + co0 + o) * LL + gy * 64 + gx] = v;
    }
}

// ---------------- channel-major GEMM: out[b][e][l] = sum_c W[e][c]*in[b][c][l]
// threads (64,4); block tile: (64*LV) l  x  (EPER*4) e
template <int K, int EPER, int LV>
__global__ __launch_bounds__(256) void k_gemm(const float* __restrict__ in,
                                              const float* __restrict__ w,
                                              float* __restrict__ out,
                                              int inbs, int outbs) {
    int tx = threadIdx.x, ty = threadIdx.y;
    int b = blockIdx.z;
    int l = blockIdx.x * (64 * LV) + tx * LV;
    int e0 = blockIdx.y * (EPER * 4) + ty * EPER;
    const float* inb = in + (size_t)b * inbs + l;
    const float* wr = w + e0 * K;
    float acc[EPER][LV];
#pragma unroll
    for (int j = 0; j < EPER; ++j)
#pragma unroll
        for (int i = 0; i < LV; ++i) acc[j][i] = 0.f;

    for (int c = 0; c < K; ++c) {
        float v[LV];
        if (LV == 4) {
            float4 t = *(const float4*)(inb + c * LL);
            v[0] = t.x; v[1] = t.y; v[2] = t.z; v[3] = t.w;
        } else {
            float2 t = *(const float2*)(inb + c * LL);
            v[0] = t.x; v[1] = t.y;
        }
#pragma unroll
        for (int j = 0; j < EPER; ++j) {
            float wv = wr[j * K + c];
#pragma unroll
            for (int i = 0; i < LV; ++i)
                acc[j][i] = fmaf(wv, v[i], acc[j][i]);
        }
    }
#pragma unroll
    for (int j = 0; j < EPER; ++j) {
        float* ob = out + (size_t)b * outbs + (size_t)(e0 + j) * LL + l;
        if (LV == 4) {
            float4 v; v.x = acc[j][0]; v.y = acc[j][1]; v.z = acc[j][2]; v.w = acc[j][3];
            *(float4*)ob = v;
        } else {
            float2 v; v.x = acc[j][0]; v.y = acc[j][1];
            *(float2*)ob = v;
        }
    }
}

// ---------------- Kernel 4: causal depthwise conv1d (k=4) + SiLU
__global__ __launch_bounds__(256) void k_conv1d(const float* __restrict__ xz,
                                                const float* __restrict__ w,
                                                const float* __restrict__ bias,
                                                float* __restrict__ xc) {
    int tid = blockIdx.x * 256 + threadIdx.x;   // B*192*1024 threads
    int tq = tid & 1023;
    int bd = tid >> 10;
    int d = bd % DIN, b = bd / DIN;
    const float* xin = xz + (size_t)(b * 384 + d) * LL;
    int t0 = tq * 4;
    float4 cur = *(const float4*)(xin + t0);
    float pm3 = 0.f, pm2 = 0.f, pm1 = 0.f;
    if (t0 > 0) {
        float4 prev = *(const float4*)(xin + t0 - 4);
        pm3 = prev.y; pm2 = prev.z; pm1 = prev.w;
    }
    float in[7] = {pm3, pm2, pm1, cur.x, cur.y, cur.z, cur.w};
    float w0 = w[d * 4 + 0], w1 = w[d * 4 + 1], w2 = w[d * 4 + 2], w3 = w[d * 4 + 3];
    float bb = bias[d];
    float o[4];
#pragma unroll
    for (int i = 0; i < 4; ++i) {
        float s = bb + w0 * in[i] + w1 * in[i + 1] + w2 * in[i + 2] + w3 * in[i + 3];
        o[i] = siluf(s);
    }
    float4 ov; ov.x = o[0]; ov.y = o[1]; ov.z = o[2]; ov.w = o[3];
    *(float4*)(xc + (size_t)(b * DIN + d) * LL + t0) = ov;
}

// ---------------- Kernel 5: x_proj -> x_dbl (B,L,38). 512 thr: 64 l x 8 e-groups
__global__ __launch_bounds__(512) void k_xproj(const float* __restrict__ xc,
                                               const float* __restrict__ xpw,
                                               float* __restrict__ xdbl) {
    int tx = threadIdx.x & 63;
    int ty = threadIdx.x >> 6;          // 0..7 (wave-uniform)
    int b = blockIdx.y;
    int l = blockIdx.x * 64 + tx;
    int e0 = ty * 5;
    const float* inb = xc + (size_t)b * DIN * LL + l;
    float acc[5] = {0.f, 0.f, 0.f, 0.f, 0.f};
    for (int c = 0; c < DIN; ++c) {
        float v = inb[c * LL];
#pragma unroll
        for (int j = 0; j < 5; ++j) {
            int e = e0 + j; if (e > 37) e = 37;   // clamp (garbage acc unused)
            acc[j] = fmaf(xpw[e * DIN + c], v, acc[j]);
        }
    }
    float* orow = xdbl + ((size_t)b * LL + l) * XE;
#pragma unroll
    for (int j = 0; j < 5; ++j)
        if (e0 + j < XE) orow[e0 + j] = acc[j];
}

// ---------------- Kernel 6: dt_proj + softplus -> delta (B,192,L)
__global__ __launch_bounds__(256) void k_dtproj(const float* __restrict__ xdbl,
                                                const float* __restrict__ dtw,
                                                const float* __restrict__ dtb,
                                                float* __restrict__ delta) {
    int tx = threadIdx.x, ty = threadIdx.y;   // (64,4)
    int b = blockIdx.y;
    int l = blockIdx.x * 64 + tx;
    int d0 = blockIdx.z * 48 + ty * 12;
    const float* dtr = xdbl + ((size_t)b * LL + l) * XE;
    float r0 = dtr[0], r1 = dtr[1], r2 = dtr[2], r3 = dtr[3], r4 = dtr[4], r5 = dtr[5];
#pragma unroll
    for (int j = 0; j < 12; ++j) {
        int dd = d0 + j;
        const float* wr2 = dtw + dd * 6;
        float s = dtb[dd] + wr2[0] * r0 + wr2[1] * r1 + wr2[2] * r2
                          + wr2[3] * r3 + wr2[4] * r4 + wr2[5] * r5;
        // softplus: ln(1+e^s) = ln2 * log2(1 + 2^(s*log2e))
        float e = exp2f(s * 1.44269504f);
        float sp = 0.69314718f * __log2f(1.f + e);
        delta[((size_t)b * DIN + dd) * LL + l] = sp;
    }
}

// ---------------- Kernel 7: chunked selective scan + gate. 32 chunks x 128 t.
// yg overwrites xz ch 0..191
#define SC_STEP(DU, UU, BB0, BB1, BB2, BB3)                              \
    {                                                                    \
        float a0 = exp2f((DU).x * A2);                                   \
        float a1 = exp2f((DU).y * A2);                                   \
        float a2 = exp2f((DU).z * A2);                                   \
        float a3 = exp2f((DU).w * A2);                                   \
        h = fmaf(a0, h, (DU).x * (UU).x * (BB0));                        \
        h = fmaf(a1, h, (DU).y * (UU).y * (BB1));                        \
        h = fmaf(a2, h, (DU).z * (UU).z * (BB2));                        \
        h = fmaf(a3, h, (DU).w * (UU).w * (BB3));                        \
        aP *= (a0 * a1) * (a2 * a3);                                     \
    }

#define SC_PSTEP(S, DU, UU, BB0, BB1, BB2, BB3, CC0, CC1, CC2, CC3, ZZ)  \
    {                                                                    \
        float a0 = exp2f((DU).x * A2);                                   \
        float a1 = exp2f((DU).y * A2);                                   \
        float a2 = exp2f((DU).z * A2);                                   \
        float a3 = exp2f((DU).w * A2);                                   \
        h = fmaf(a0, h, (DU).x * (UU).x * (BB0)); float p0 = h * (CC0);  \
        h = fmaf(a1, h, (DU).y * (UU).y * (BB1)); float p1 = h * (CC1);  \
        h = fmaf(a2, h, (DU).z * (UU).z * (BB2)); float p2 = h * (CC2);  \
        h = fmaf(a3, h, (DU).w * (UU).w * (BB3)); float p3 = h * (CC3);  \
        p0 += __shfl_xor(p0, 1); p0 += __shfl_xor(p0, 2);                \
        p0 += __shfl_xor(p0, 4); p0 += __shfl_xor(p0, 8);                \
        p1 += __shfl_xor(p1, 1); p1 += __shfl_xor(p1, 2);                \
        p1 += __shfl_xor(p1, 4); p1 += __shfl_xor(p1, 8);                \
        p2 += __shfl_xor(p2, 1); p2 += __shfl_xor(p2, 2);                \
        p2 += __shfl_xor(p2, 4); p2 += __shfl_xor(p2, 8);                \
        p3 += __shfl_xor(p3, 1); p3 += __shfl_xor(p3, 2);                \
        p3 += __shfl_xor(p3, 4); p3 += __shfl_xor(p3, 8);                \
        float y0 = fmaf(Dd, (UU).x, p0) * siluf((ZZ).x);                 \
        float y1 = fmaf(Dd, (UU).y, p1) * siluf((ZZ).y);                 \
        float y2 = fmaf(Dd, (UU).z, p2) * siluf((ZZ).z);                 \
        float y3 = fmaf(Dd, (UU).w, p3) * siluf((ZZ).w);                 \
        if (n == 0) {                                                    \
            float4 ov; ov.x = y0; ov.y = y1; ov.z = y2; ov.w = y3;       \
            *(float4*)(yrow + t0 + (S) * 4) = ov;                        \
        }                                                                \
    }

__global__ __launch_bounds__(512, 6) void k_scan(const float* __restrict__ delta,
                                                 const float* __restrict__ xc,
                                                 const float* __restrict__ xdbl,
                                                 const float* __restrict__ A_log,
                                                 const float* __restrict__ Dp,
                                                 float* __restrict__ xz) {
    __shared__ float s_d[32 * 132];       // chunk c at c*132 (+4 pad: bank-spread cg)
    __shared__ float s_u[32 * 132];
    __shared__ float s_a[32][17];
    __shared__ float s_h[32][17];
    int tid = threadIdx.x;
    int n = tid & 15, cg = tid >> 4;      // 32 chunks x 16 states
    int bd = blockIdx.x;
    int d = bd % DIN, b = bd / DIN;
    const float* drow = delta + (size_t)(b * DIN + d) * LL;
    const float* urow = xc    + (size_t)(b * DIN + d) * LL;
    const float* zrow = xz    + (size_t)(b * 384 + DIN + d) * LL;
    float* yrow       = xz    + (size_t)(b * 384 + d) * LL;
    const float* xd   = xdbl  + (size_t)b * LL * XE;
    float A2 = -__expf(A_log[d * NST + n]) * 1.44269504f;   // for exp2f
    float Dd = Dp[d];

    // stage delta & u rows into LDS (read once from HBM instead of twice)
    {
        int t8 = tid * 8;
        int li = ((t8 >> 7) * 132) + (t8 & 127);
        *(float4*)&s_d[li]     = *(const float4*)(drow + t8);
        *(float4*)&s_d[li + 4] = *(const float4*)(drow + t8 + 4);
        *(float4*)&s_u[li]     = *(const float4*)(urow + t8);
        *(float4*)&s_u[li + 4] = *(const float4*)(urow + t8 + 4);
    }
    __syncthreads();

    const float* xB = xd + 6 + n;
    const float* xC = xd + 22 + n;
    int t0 = cg * 128;
    int lb = cg * 132;

    // ---- phase 1: per-chunk aggregates (software-pipelined, 4 t / step)
    float h = 0.f, aP = 1.f;
    float4 du_c = *(float4*)&s_d[lb];
    float4 u_c  = *(float4*)&s_u[lb];
    int tb = t0 * XE;
    float B0 = xB[tb], B1 = xB[tb + XE], B2 = xB[tb + 2 * XE], B3 = xB[tb + 3 * XE];
    for (int s = 0; s < 31; ++s) {
        int ln = lb + s * 4 + 4;
        int tn = (t0 + s * 4 + 4) * XE;
        float4 du_n = *(float4*)&s_d[ln];
        float4 u_n  = *(float4*)&s_u[ln];
        float Bn0 = xB[tn], Bn1 = xB[tn + XE], Bn2 = xB[tn + 2 * XE], Bn3 = xB[tn + 3 * XE];
        SC_STEP(du_c, u_c, B0, B1, B2, B3);
        du_c = du_n; u_c = u_n; B0 = Bn0; B1 = Bn1; B2 = Bn2; B3 = Bn3;
    }
    SC_STEP(du_c, u_c, B0, B1, B2, B3);
    s_a[cg][n] = aP;
    s_h[cg][n] = h;
    __syncthreads();

    // ---- phase 2: Kogge-Stone scan of 32 chunk aggregates (per n)
    {
        int l = tid & 63, w = tid >> 6;       // 8 waves, 2 n's each
        int c = l & 31, nn = (w << 1) | (l >> 5);
        float a  = s_a[c][nn];
        float hh = s_h[c][nn];
#pragma unroll
        for (int st = 1; st < 32; st <<= 1) {
            float ap = __shfl_up(a, st, 32);
            float hp = __shfl_up(hh, st, 32);
            bool ok = (c >= st);
            hh = ok ? fmaf(a, hp, hh) : hh;
            a  = ok ? a * ap : a;
        }
        float h0 = __shfl_up(hh, 1, 32);
        if (c == 0) h0 = 0.f;
        s_a[c][nn] = h0;                      // reuse s_a for h0
    }
    __syncthreads();

    // ---- phase 3: recompute with correct h0; reduce over n; gate; store
    h = s_a[cg][n];
    du_c = *(float4*)&s_d[lb];
    u_c  = *(float4*)&s_u[lb];
    B0 = xB[tb]; B1 = xB[tb + XE]; B2 = xB[tb + 2 * XE]; B3 = xB[tb + 3 * XE];
    float C0 = xC[tb], C1 = xC[tb + XE], C2 = xC[tb + 2 * XE], C3 = xC[tb + 3 * XE];
    float4 z_c = *(const float4*)(zrow + t0);
    for (int s = 0; s < 31; ++s) {
        int ln = lb + s * 4 + 4;
        int tn = (t0 + s * 4 + 4) * XE;
        float4 du_n = *(float4*)&s_d[ln];
        float4 u_n  = *(float4*)&s_u[ln];
        float Bn0 = xB[tn], Bn1 = xB[tn + XE], Bn2 = xB[tn + 2 * XE], Bn3 = xB[tn + 3 * XE];
        float Cn0 = xC[tn], Cn1 = xC[tn + XE], Cn2 = xC[tn + 2 * XE], Cn3 = xC[tn + 3 * XE];
        float4 z_n = *(const float4*)(zrow + t0 + s * 4 + 4);
        SC_PSTEP(s, du_c, u_c, B0, B1, B2, B3, C0, C1, C2, C3, z_c);
        du_c = du_n; u_c = u_n; z_c = z_n;
        B0 = Bn0; B1 = Bn1; B2 = Bn2; B3 = Bn3;
        C0 = Cn0; C1 = Cn1; C2 = Cn2; C3 = Cn3;
    }
    SC_PSTEP(31, du_c, u_c, B0, B1, B2, B3, C0, C1, C2, C3, z_c);
}

extern "C" void kernel_launch(void* const* d_in, const int* in_sizes, int n_in,
                              void* d_out, int out_size, void* d_ws, size_t ws_size,
                              hipStream_t stream) {
    const float* x         = (const float*)d_in[0];
    const float* proj_w    = (const float*)d_in[1];
    const float* dconv_w   = (const float*)d_in[2];
    const float* in_proj_w = (const float*)d_in[3];
    const float* conv1d_w  = (const float*)d_in[4];
    const float* conv1d_b  = (const float*)d_in[5];
    const float* x_proj_w  = (const float*)d_in[6];
    const float* dt_proj_w = (const float*)d_in[7];
    const float* dt_proj_b = (const float*)d_in[8];
    const float* A_log     = (const float*)d_in[9];
    const float* Dp        = (const float*)d_in[10];
    const float* out_proj_w= (const float*)d_in[11];
    float* out = (float*)d_out;
    float* ws  = (float*)d_ws;

    float* Wm   = ws;                    // 82,944
    float* seq  = Wm + 82944;            // 4*96*4096   = 1,572,864
    float* xz   = seq + 1572864;         // 4*384*4096  = 6,291,456 (xin -> later yg; z upper)
    float* xc   = xz + 6291456;          // 4*192*4096  = 3,145,728
    float* xdbl = xc + 3145728;          // 4*4096*38   =   622,592
    float* delta= xdbl + 622592;         // 4*192*4096  = 3,145,728

    k_merge_w<<<dim3(324), dim3(256), 0, stream>>>(proj_w, dconv_w, Wm);
    k_conv3x3<<<dim3(8, 16, 4), dim3(256), 0, stream>>>(x, Wm, seq);
    k_gemm<96, 4, 4><<<dim3(16, 24, 4), dim3(64, 4), 0, stream>>>(seq, in_proj_w, xz,
                                                                  96 * LL, 384 * LL);
    k_conv1d<<<dim3(3072), dim3(256), 0, stream>>>(xz, conv1d_w, conv1d_b, xc);
    k_xproj<<<dim3(64, 4), dim3(512), 0, stream>>>(xc, x_proj_w, xdbl);
    k_dtproj<<<dim3(64, 4, 4), dim3(64, 4), 0, stream>>>(xdbl, dt_proj_w, dt_proj_b, delta);
    k_scan<<<dim3(768), dim3(512), 0, stream>>>(delta, xc, xdbl, A_log, Dp, xz);
    k_gemm<192, 4, 2><<<dim3(32, 6, 4), dim3(64, 4), 0, stream>>>(xz, out_proj_w, out,
                                                                  384 * LL, 96 * LL);
}

// Round 3
// 192.079 us; speedup vs baseline: 3.2490x; 1.7241x over previous
//
#include <hip/hip_runtime.h>
#include <math.h>

#define LL    4096
#define CDIM  96
#define DIN   192
#define NST   16
#define XE    38   // dt_rank(6) + 2*16

typedef __attribute__((ext_vector_type(8))) short v8s;
typedef __attribute__((ext_vector_type(4))) float v4f;
typedef unsigned short ushort_t;
typedef unsigned int uint_t;

__device__ __forceinline__ float siluf(float x) {
    return x * __builtin_amdgcn_rcpf(1.f + __expf(-x));
}
__device__ __forceinline__ ushort_t f2bf(float f) {
    uint_t u = __builtin_bit_cast(uint_t, f);
    return (ushort_t)((u + 0x7fffu + ((u >> 16) & 1u)) >> 16);
}

// ---------------- Kernel 1: merge proj(1x1) into dconv(3x3) -> Wbf[tap][co][ci] bf16
__global__ __launch_bounds__(256) void k_merge_w(const float* __restrict__ proj_w,
                                                 const float* __restrict__ dconv_w,
                                                 ushort_t* __restrict__ Wbf) {
    int idx = blockIdx.x * 256 + threadIdx.x;       // o*96*9 + c*9 + k
    if (idx >= 96 * 96 * 9) return;
    int k = idx % 9;
    int c = (idx / 9) % 96;
    int o = idx / (9 * 96);
    float s = 0.f;
    for (int i = 0; i < 192; ++i)
        s += dconv_w[(o * 192 + i) * 9 + k] * proj_w[i * 96 + c];
    Wbf[(k * 96 + o) * 96 + c] = f2bf(s);
}

// ---------------- Kernel 1b: f32 -> bf16 weight copy
__global__ __launch_bounds__(256) void k_cvt_w(const float* __restrict__ w,
                                               ushort_t* __restrict__ o, int nelem) {
    int i = blockIdx.x * 256 + threadIdx.x;
    if (i < nelem) o[i] = f2bf(w[i]);
}

// ---------------- Kernel 2a: x (B,96,64,64) f32 -> xT[b][66][68][96] bf16, zero halo
__global__ __launch_bounds__(256) void k_xpad(const float* __restrict__ x,
                                              ushort_t* __restrict__ xT) {
    int yy = blockIdx.x;        // 0..65
    int b  = blockIdx.y;
    int yv = yy - 1;
    for (int i = threadIdx.x; i < 68 * 12; i += 256) {
        int xx = i % 68, cig = i / 68;
        int xv = xx - 1;
        ushort_t u[8];
        if (yv >= 0 && yv < 64 && xv >= 0 && xv < 64) {
            const float* sp = x + ((size_t)(b * 96 + cig * 8)) * LL + yv * 64 + xv;
#pragma unroll
            for (int j = 0; j < 8; ++j) u[j] = f2bf(sp[j * LL]);
        } else {
#pragma unroll
            for (int j = 0; j < 8; ++j) u[j] = 0;
        }
        uint4 pk;
        pk.x = u[0] | ((uint_t)u[1] << 16); pk.y = u[2] | ((uint_t)u[3] << 16);
        pk.z = u[4] | ((uint_t)u[5] << 16); pk.w = u[6] | ((uint_t)u[7] << 16);
        *(uint4*)(xT + (((size_t)b * 66 + yy) * 68 + xx) * 96 + cig * 8) = pk;
    }
}

// ---------------- Kernel 2b: implicit-GEMM 3x3 conv via MFMA bf16 -> seqT[b][l][c] bf16
// 512 blocks x 6 waves: (b, y, half-row); wave = 16 px x 32 co, K = 864 (9 taps x 96 ci)
__global__ __launch_bounds__(384, 2) void k_conv_mfma(const ushort_t* __restrict__ xT,
                                                      const ushort_t* __restrict__ Wbf,
                                                      ushort_t* __restrict__ seqT) {
    int tid = threadIdx.x;
    int w = tid >> 6, l = tid & 63;
    int n = l & 15, g = l >> 4;
    int blk = blockIdx.x;
    int b = blk >> 7, rem = blk & 127;
    int y = rem >> 1, half = rem & 1;
    int x0 = (half * 2 + (w & 1)) * 16;
    int co0 = (w >> 1) * 32;
    v4f acc0 = {0.f, 0.f, 0.f, 0.f};
    v4f acc1 = {0.f, 0.f, 0.f, 0.f};
    const ushort_t* xb = xT + (((size_t)b * 66 + y) * 68 + x0 + n) * 96 + g * 8;
    const ushort_t* aw = Wbf + ((size_t)co0 + (l & 15)) * 96 + g * 8;
#pragma unroll
    for (int tap = 0; tap < 9; ++tap) {
        int dy = tap / 3, dx = tap % 3;
        const ushort_t* bp = xb + (dy * 68 + dx) * 96;
        const ushort_t* ap = aw + (size_t)tap * 96 * 96;
#pragma unroll
        for (int kk = 0; kk < 3; ++kk) {
            v8s bf = *(const v8s*)(bp + kk * 32);
            v8s a0 = *(const v8s*)(ap + kk * 32);
            v8s a1 = *(const v8s*)(ap + 16 * 96 + kk * 32);
            acc0 = __builtin_amdgcn_mfma_f32_16x16x32_bf16(a0, bf, acc0, 0, 0, 0);
            acc1 = __builtin_amdgcn_mfma_f32_16x16x32_bf16(a1, bf, acc1, 0, 0, 0);
        }
    }
    size_t sb = ((size_t)b * 4096 + y * 64 + x0 + n) * 96;
    ushort4 p0, p1;
    p0.x = f2bf(acc0[0]); p0.y = f2bf(acc0[1]); p0.z = f2bf(acc0[2]); p0.w = f2bf(acc0[3]);
    p1.x = f2bf(acc1[0]); p1.y = f2bf(acc1[1]); p1.z = f2bf(acc1[2]); p1.w = f2bf(acc1[3]);
    *(ushort4*)(seqT + sb + co0 + g * 4) = p0;
    *(ushort4*)(seqT + sb + co0 + 16 + g * 4) = p1;
}

// ---------------- Kernel 3: in_proj via MFMA: xz[b][e][l] f32 = sum_c W[e][c] seqT[b][l][c]
// 1024 blocks x 4 waves: wave = 16 l x 96 e, K = 96
__global__ __launch_bounds__(256, 3) void k_inproj(const ushort_t* __restrict__ seqT,
                                                   const ushort_t* __restrict__ Wibf,
                                                   float* __restrict__ xz) {
    int tid = threadIdx.x;
    int w = tid >> 6, l = tid & 63;
    int n = l & 15, g = l >> 4;
    int blk = blockIdx.x;
    int b = blk >> 8;
    int l0 = (blk & 255) * 16;
    int coh = w * 96;
    v4f acc[6];
#pragma unroll
    for (int mt = 0; mt < 6; ++mt) acc[mt] = (v4f){0.f, 0.f, 0.f, 0.f};
    const ushort_t* bp = seqT + ((size_t)b * 4096 + l0 + n) * 96 + g * 8;
    const ushort_t* ap = Wibf + ((size_t)coh + (l & 15)) * 96 + g * 8;
#pragma unroll
    for (int kk = 0; kk < 3; ++kk) {
        v8s bf = *(const v8s*)(bp + kk * 32);
#pragma unroll
        for (int mt = 0; mt < 6; ++mt) {
            v8s af = *(const v8s*)(ap + mt * 16 * 96 + kk * 32);
            acc[mt] = __builtin_amdgcn_mfma_f32_16x16x32_bf16(af, bf, acc[mt], 0, 0, 0);
        }
    }
    float* ob = xz + (size_t)b * 384 * LL + l0 + n;
#pragma unroll
    for (int mt = 0; mt < 6; ++mt) {
        int e = coh + mt * 16 + g * 4;
#pragma unroll
        for (int r = 0; r < 4; ++r)
            ob[(size_t)(e + r) * LL] = acc[mt][r];
    }
}

// ---------------- channel-major f32 GEMM (used for out_proj)
template <int K, int EPER, int LV>
__global__ __launch_bounds__(256) void k_gemm(const float* __restrict__ in,
                                              const float* __restrict__ w,
                                              float* __restrict__ out,
                                              int inbs, int outbs) {
    int tx = threadIdx.x, ty = threadIdx.y;
    int b = blockIdx.z;
    int l = blockIdx.x * (64 * LV) + tx * LV;
    int e0 = blockIdx.y * (EPER * 4) + ty * EPER;
    const float* inb = in + (size_t)b * inbs + l;
    const float* wr = w + e0 * K;
    float acc[EPER][LV];
#pragma unroll
    for (int j = 0; j < EPER; ++j)
#pragma unroll
        for (int i = 0; i < LV; ++i) acc[j][i] = 0.f;

    for (int c = 0; c < K; ++c) {
        float v[LV];
        if (LV == 4) {
            float4 t = *(const float4*)(inb + c * LL);
            v[0] = t.x; v[1] = t.y; v[2] = t.z; v[3] = t.w;
        } else {
            float2 t = *(const float2*)(inb + c * LL);
            v[0] = t.x; v[1] = t.y;
        }
#pragma unroll
        for (int j = 0; j < EPER; ++j) {
            float wv = wr[j * K + c];
#pragma unroll
            for (int i = 0; i < LV; ++i)
                acc[j][i] = fmaf(wv, v[i], acc[j][i]);
        }
    }
#pragma unroll
    for (int j = 0; j < EPER; ++j) {
        float* ob = out + (size_t)b * outbs + (size_t)(e0 + j) * LL + l;
        if (LV == 4) {
            float4 v; v.x = acc[j][0]; v.y = acc[j][1]; v.z = acc[j][2]; v.w = acc[j][3];
            *(float4*)ob = v;
        } else {
            float2 v; v.x = acc[j][0]; v.y = acc[j][1];
            *(float2*)ob = v;
        }
    }
}

// ---------------- Kernel 4: causal depthwise conv1d (k=4) + SiLU
__global__ __launch_bounds__(256) void k_conv1d(const float* __restrict__ xz,
                                                const float* __restrict__ w,
                                                const float* __restrict__ bias,
                                                float* __restrict__ xc) {
    int tid = blockIdx.x * 256 + threadIdx.x;   // B*192*1024 threads
    int tq = tid & 1023;
    int bd = tid >> 10;
    int d = bd % DIN, b = bd / DIN;
    const float* xin = xz + (size_t)(b * 384 + d) * LL;
    int t0 = tq * 4;
    float4 cur = *(const float4*)(xin + t0);
    float pm3 = 0.f, pm2 = 0.f, pm1 = 0.f;
    if (t0 > 0) {
        float4 prev = *(const float4*)(xin + t0 - 4);
        pm3 = prev.y; pm2 = prev.z; pm1 = prev.w;
    }
    float in[7] = {pm3, pm2, pm1, cur.x, cur.y, cur.z, cur.w};
    float w0 = w[d * 4 + 0], w1 = w[d * 4 + 1], w2 = w[d * 4 + 2], w3 = w[d * 4 + 3];
    float bb = bias[d];
    float o[4];
#pragma unroll
    for (int i = 0; i < 4; ++i) {
        float s = bb + w0 * in[i] + w1 * in[i + 1] + w2 * in[i + 2] + w3 * in[i + 3];
        o[i] = siluf(s);
    }
    float4 ov; ov.x = o[0]; ov.y = o[1]; ov.z = o[2]; ov.w = o[3];
    *(float4*)(xc + (size_t)(b * DIN + d) * LL + t0) = ov;
}

// ---------------- Kernel 5: x_proj -> x_dbl (B,L,38). 512 thr: 64 l x 8 e-groups
__global__ __launch_bounds__(512) void k_xproj(const float* __restrict__ xc,
                                               const float* __restrict__ xpw,
                                               float* __restrict__ xdbl) {
    int tx = threadIdx.x & 63;
    int ty = threadIdx.x >> 6;          // 0..7 (wave-uniform)
    int b = blockIdx.y;
    int l = blockIdx.x * 64 + tx;
    int e0 = ty * 5;
    const float* inb = xc + (size_t)b * DIN * LL + l;
    float acc[5] = {0.f, 0.f, 0.f, 0.f, 0.f};
    for (int c = 0; c < DIN; ++c) {
        float v = inb[c * LL];
#pragma unroll
        for (int j = 0; j < 5; ++j) {
            int e = e0 + j; if (e > 37) e = 37;   // clamp (garbage acc unused)
            acc[j] = fmaf(xpw[e * DIN + c], v, acc[j]);
        }
    }
    float* orow = xdbl + ((size_t)b * LL + l) * XE;
#pragma unroll
    for (int j = 0; j < 5; ++j)
        if (e0 + j < XE) orow[e0 + j] = acc[j];
}

// ---------------- Kernel 6: dt_proj + softplus -> delta (B,192,L)
__global__ __launch_bounds__(256) void k_dtproj(const float* __restrict__ xdbl,
                                                const float* __restrict__ dtw,
                                                const float* __restrict__ dtb,
                                                float* __restrict__ delta) {
    int tx = threadIdx.x, ty = threadIdx.y;   // (64,4)
    int b = blockIdx.y;
    int l = blockIdx.x * 64 + tx;
    int d0 = blockIdx.z * 48 + ty * 12;
    const float* dtr = xdbl + ((size_t)b * LL + l) * XE;
    float r0 = dtr[0], r1 = dtr[1], r2 = dtr[2], r3 = dtr[3], r4 = dtr[4], r5 = dtr[5];
#pragma unroll
    for (int j = 0; j < 12; ++j) {
        int dd = d0 + j;
        const float* wr2 = dtw + dd * 6;
        float s = dtb[dd] + wr2[0] * r0 + wr2[1] * r1 + wr2[2] * r2
                          + wr2[3] * r3 + wr2[4] * r4 + wr2[5] * r5;
        float e = exp2f(s * 1.44269504f);
        float sp = 0.69314718f * __log2f(1.f + e);
        delta[((size_t)b * DIN + dd) * LL + l] = sp;
    }
}

// ---------------- Kernel 7: chunked selective scan + gate. 32 chunks x 128 t.
#define SC_STEP(DU, UU, BB0, BB1, BB2, BB3)                              \
    {                                                                    \
        float a0 = exp2f((DU).x * A2);                                   \
        float a1 = exp2f((DU).y * A2);                                   \
        float a2 = exp2f((DU).z * A2);                                   \
        float a3 = exp2f((DU).w * A2);                                   \
        h = fmaf(a0, h, (DU).x * (UU).x * (BB0));                        \
        h = fmaf(a1, h, (DU).y * (UU).y * (BB1));                        \
        h = fmaf(a2, h, (DU).z * (UU).z * (BB2));                        \
        h = fmaf(a3, h, (DU).w * (UU).w * (BB3));                        \
        aP *= (a0 * a1) * (a2 * a3);                                     \
    }

#define SC_PSTEP(S, DU, UU, BB0, BB1, BB2, BB3, CC0, CC1, CC2, CC3, ZZ)  \
    {                                                                    \
        float a0 = exp2f((DU).x * A2);                                   \
        float a1 = exp2f((DU).y * A2);                                   \
        float a2 = exp2f((DU).z * A2);                                   \
        float a3 = exp2f((DU).w * A2);                                   \
        h = fmaf(a0, h, (DU).x * (UU).x * (BB0)); float p0 = h * (CC0);  \
        h = fmaf(a1, h, (DU).y * (UU).y * (BB1)); float p1 = h * (CC1);  \
        h = fmaf(a2, h, (DU).z * (UU).z * (BB2)); float p2 = h * (CC2);  \
        h = fmaf(a3, h, (DU).w * (UU).w * (BB3)); float p3 = h * (CC3);  \
        p0 += __shfl_xor(p0, 1); p0 += __shfl_xor(p0, 2);                \
        p0 += __shfl_xor(p0, 4); p0 += __shfl_xor(p0, 8);                \
        p1 += __shfl_xor(p1, 1); p1 += __shfl_xor(p1, 2);                \
        p1 += __shfl_xor(p1, 4); p1 += __shfl_xor(p1, 8);                \
        p2 += __shfl_xor(p2, 1); p2 += __shfl_xor(p2, 2);                \
        p2 += __shfl_xor(p2, 4); p2 += __shfl_xor(p2, 8);                \
        p3 += __shfl_xor(p3, 1); p3 += __shfl_xor(p3, 2);                \
        p3 += __shfl_xor(p3, 4); p3 += __shfl_xor(p3, 8);                \
        float y0 = fmaf(Dd, (UU).x, p0) * siluf((ZZ).x);                 \
        float y1 = fmaf(Dd, (UU).y, p1) * siluf((ZZ).y);                 \
        float y2 = fmaf(Dd, (UU).z, p2) * siluf((ZZ).z);                 \
        float y3 = fmaf(Dd, (UU).w, p3) * siluf((ZZ).w);                 \
        if (n == 0) {                                                    \
            float4 ov; ov.x = y0; ov.y = y1; ov.z = y2; ov.w = y3;       \
            *(float4*)(yrow + t0 + (S) * 4) = ov;                        \
        }                                                                \
    }

__global__ __launch_bounds__(512, 6) void k_scan(const float* __restrict__ delta,
                                                 const float* __restrict__ xc,
                                                 const float* __restrict__ xdbl,
                                                 const float* __restrict__ A_log,
                                                 const float* __restrict__ Dp,
                                                 float* __restrict__ xz) {
    __shared__ float s_d[32 * 132];       // chunk c at c*132 (+4 pad)
    __shared__ float s_u[32 * 132];
    __shared__ float s_a[32][17];
    __shared__ float s_h[32][17];
    int tid = threadIdx.x;
    int n = tid & 15, cg = tid >> 4;      // 32 chunks x 16 states
    int bd = blockIdx.x;
    int d = bd % DIN, b = bd / DIN;
    const float* drow = delta + (size_t)(b * DIN + d) * LL;
    const float* urow = xc    + (size_t)(b * DIN + d) * LL;
    const float* zrow = xz    + (size_t)(b * 384 + DIN + d) * LL;
    float* yrow       = xz    + (size_t)(b * 384 + d) * LL;
    const float* xd   = xdbl  + (size_t)b * LL * XE;
    float A2 = -__expf(A_log[d * NST + n]) * 1.44269504f;   // for exp2f
    float Dd = Dp[d];

    {
        int t8 = tid * 8;
        int li = ((t8 >> 7) * 132) + (t8 & 127);
        *(float4*)&s_d[li]     = *(const float4*)(drow + t8);
        *(float4*)&s_d[li + 4] = *(const float4*)(drow + t8 + 4);
        *(float4*)&s_u[li]     = *(const float4*)(urow + t8);
        *(float4*)&s_u[li + 4] = *(const float4*)(urow + t8 + 4);
    }
    __syncthreads();

    const float* xB = xd + 6 + n;
    const float* xC = xd + 22 + n;
    int t0 = cg * 128;
    int lb = cg * 132;

    // ---- phase 1
    float h = 0.f, aP = 1.f;
    float4 du_c = *(float4*)&s_d[lb];
    float4 u_c  = *(float4*)&s_u[lb];
    int tb = t0 * XE;
    float B0 = xB[tb], B1 = xB[tb + XE], B2 = xB[tb + 2 * XE], B3 = xB[tb + 3 * XE];
    for (int s = 0; s < 31; ++s) {
        int ln = lb + s * 4 + 4;
        int tn = (t0 + s * 4 + 4) * XE;
        float4 du_n = *(float4*)&s_d[ln];
        float4 u_n  = *(float4*)&s_u[ln];
        float Bn0 = xB[tn], Bn1 = xB[tn + XE], Bn2 = xB[tn + 2 * XE], Bn3 = xB[tn + 3 * XE];
        SC_STEP(du_c, u_c, B0, B1, B2, B3);
        du_c = du_n; u_c = u_n; B0 = Bn0; B1 = Bn1; B2 = Bn2; B3 = Bn3;
    }
    SC_STEP(du_c, u_c, B0, B1, B2, B3);
    s_a[cg][n] = aP;
    s_h[cg][n] = h;
    __syncthreads();

    // ---- phase 2: Kogge-Stone scan of 32 chunk aggregates (per n)
    {
        int l = tid & 63, w = tid >> 6;
        int c = l & 31, nn = (w << 1) | (l >> 5);
        float a  = s_a[c][nn];
        float hh = s_h[c][nn];
#pragma unroll
        for (int st = 1; st < 32; st <<= 1) {
            float ap = __shfl_up(a, st, 32);
            float hp = __shfl_up(hh, st, 32);
            bool ok = (c >= st);
            hh = ok ? fmaf(a, hp, hh) : hh;
            a  = ok ? a * ap : a;
        }
        float h0 = __shfl_up(hh, 1, 32);
        if (c == 0) h0 = 0.f;
        s_a[c][nn] = h0;
    }
    __syncthreads();

    // ---- phase 3
    h = s_a[cg][n];
    du_c = *(float4*)&s_d[lb];
    u_c  = *(float4*)&s_u[lb];
    B0 = xB[tb]; B1 = xB[tb + XE]; B2 = xB[tb + 2 * XE]; B3 = xB[tb + 3 * XE];
    float C0 = xC[tb], C1 = xC[tb + XE], C2 = xC[tb + 2 * XE], C3 = xC[tb + 3 * XE];
    float4 z_c = *(const float4*)(zrow + t0);
    for (int s = 0; s < 31; ++s) {
        int ln = lb + s * 4 + 4;
        int tn = (t0 + s * 4 + 4) * XE;
        float4 du_n = *(float4*)&s_d[ln];
        float4 u_n  = *(float4*)&s_u[ln];
        float Bn0 = xB[tn], Bn1 = xB[tn + XE], Bn2 = xB[tn + 2 * XE], Bn3 = xB[tn + 3 * XE];
        float Cn0 = xC[tn], Cn1 = xC[tn + XE], Cn2 = xC[tn + 2 * XE], Cn3 = xC[tn + 3 * XE];
        float4 z_n = *(const float4*)(zrow + t0 + s * 4 + 4);
        SC_PSTEP(s, du_c, u_c, B0, B1, B2, B3, C0, C1, C2, C3, z_c);
        du_c = du_n; u_c = u_n; z_c = z_n;
        B0 = Bn0; B1 = Bn1; B2 = Bn2; B3 = Bn3;
        C0 = Cn0; C1 = Cn1; C2 = Cn2; C3 = Cn3;
    }
    SC_PSTEP(31, du_c, u_c, B0, B1, B2, B3, C0, C1, C2, C3, z_c);
}

extern "C" void kernel_launch(void* const* d_in, const int* in_sizes, int n_in,
                              void* d_out, int out_size, void* d_ws, size_t ws_size,
                              hipStream_t stream) {
    const float* x         = (const float*)d_in[0];
    const float* proj_w    = (const float*)d_in[1];
    const float* dconv_w   = (const float*)d_in[2];
    const float* in_proj_w = (const float*)d_in[3];
    const float* conv1d_w  = (const float*)d_in[4];
    const float* conv1d_b  = (const float*)d_in[5];
    const float* x_proj_w  = (const float*)d_in[6];
    const float* dt_proj_w = (const float*)d_in[7];
    const float* dt_proj_b = (const float*)d_in[8];
    const float* A_log     = (const float*)d_in[9];
    const float* Dp        = (const float*)d_in[10];
    const float* out_proj_w= (const float*)d_in[11];
    float* out = (float*)d_out;
    float* ws  = (float*)d_ws;

    // carve (float units)
    ushort_t* Wbf  = (ushort_t*)ws;                      // 82,944 sh   -> 41,472 fl
    ushort_t* Wibf = (ushort_t*)(ws + 41472);            // 36,864 sh   -> 18,432 fl
    ushort_t* xT   = (ushort_t*)(ws + 59904);            // 1,723,392 sh-> 861,696 fl
    ushort_t* seqT = (ushort_t*)(ws + 921600);           // 1,572,864 sh-> 786,432 fl
    float* xz   = ws + 1708032;                          // 4*384*4096 = 6,291,456
    float* xc   = xz + 6291456;                          // 3,145,728
    float* xdbl = xc + 3145728;                          //   622,592
    float* delta= xdbl + 622592;                         // 3,145,728

    k_merge_w<<<dim3(324), dim3(256), 0, stream>>>(proj_w, dconv_w, Wbf);
    k_cvt_w<<<dim3(144), dim3(256), 0, stream>>>(in_proj_w, Wibf, 384 * 96);
    k_xpad<<<dim3(66, 4), dim3(256), 0, stream>>>(x, xT);
    k_conv_mfma<<<dim3(512), dim3(384), 0, stream>>>(xT, Wbf, seqT);
    k_inproj<<<dim3(1024), dim3(256), 0, stream>>>(seqT, Wibf, xz);
    k_conv1d<<<dim3(3072), dim3(256), 0, stream>>>(xz, conv1d_w, conv1d_b, xc);
    k_xproj<<<dim3(64, 4), dim3(512), 0, stream>>>(xc, x_proj_w, xdbl);
    k_dtproj<<<dim3(64, 4, 4), dim3(64, 4), 0, stream>>>(xdbl, dt_proj_w, dt_proj_b, delta);
    k_scan<<<dim3(768), dim3(512), 0, stream>>>(delta, xc, xdbl, A_log, Dp, xz);
    k_gemm<192, 4, 2><<<dim3(32, 6, 4), dim3(64, 4), 0, stream>>>(xz, out_proj_w, out,
                                                                  384 * LL, 96 * LL);
}

// Round 5
// 157.246 us; speedup vs baseline: 3.9687x; 1.2215x over previous
//
#include <hip/hip_runtime.h>
#include <math.h>

#define LL    4096
#define CDIM  96
#define DIN   192
#define NST   16
#define XE    38   // dt_rank(6) + 2*16

typedef __attribute__((ext_vector_type(8))) short v8s;
typedef __attribute__((ext_vector_type(4))) float v4f;
typedef unsigned short ushort_t;
typedef unsigned int uint_t;

#if __has_builtin(__builtin_amdgcn_exp2f)
__device__ __forceinline__ float fexp2(float x) { return __builtin_amdgcn_exp2f(x); }
#else
__device__ __forceinline__ float fexp2(float x) { return exp2f(x); }
#endif
#if __has_builtin(__builtin_amdgcn_logf)
__device__ __forceinline__ float flog2(float x) { return __builtin_amdgcn_logf(x); }
#else
__device__ __forceinline__ float flog2(float x) { return __log2f(x); }
#endif

__device__ __forceinline__ float siluf(float x) {
    return x * __builtin_amdgcn_rcpf(1.f + fexp2(-1.44269504f * x));
}
__device__ __forceinline__ ushort_t f2bf(float f) {
    uint_t u = __builtin_bit_cast(uint_t, f);
    return (ushort_t)((u + 0x7fffu + ((u >> 16) & 1u)) >> 16);
}

// ---------------- Kernel 1: merge proj(1x1) into dconv(3x3) -> Wbf[tap][co][ci] bf16
__global__ __launch_bounds__(256) void k_merge_w(const float* __restrict__ proj_w,
                                                 const float* __restrict__ dconv_w,
                                                 ushort_t* __restrict__ Wbf) {
    int idx = blockIdx.x * 256 + threadIdx.x;       // o*96*9 + c*9 + k
    if (idx >= 96 * 96 * 9) return;
    int k = idx % 9;
    int c = (idx / 9) % 96;
    int o = idx / (9 * 96);
    float s = 0.f;
    for (int i = 0; i < 192; ++i)
        s += dconv_w[(o * 192 + i) * 9 + k] * proj_w[i * 96 + c];
    Wbf[(k * 96 + o) * 96 + c] = f2bf(s);
}

// ---------------- Kernel 1b: all weight f32->bf16 conversions in one launch
__global__ __launch_bounds__(256) void k_cvt_all(const float* __restrict__ in_proj_w,
                                                 const float* __restrict__ out_proj_w,
                                                 const float* __restrict__ x_proj_w,
                                                 ushort_t* __restrict__ Wibf,
                                                 ushort_t* __restrict__ Wobf,
                                                 ushort_t* __restrict__ Wxbf) {
    int i = blockIdx.x * 256 + threadIdx.x;
    if (i < 36864) { Wibf[i] = f2bf(in_proj_w[i]); return; }
    i -= 36864;
    if (i < 18432) { Wobf[i] = f2bf(out_proj_w[i]); return; }
    i -= 18432;
    if (i < 9216) {
        int e = i / 192;
        Wxbf[i] = (e < XE) ? f2bf(x_proj_w[i]) : (ushort_t)0;
    }
}

// ---------------- Kernel 2a: x (B,96,64,64) f32 -> xT[b][66][68][96] bf16, zero halo
__global__ __launch_bounds__(256) void k_xpad(const float* __restrict__ x,
                                              ushort_t* __restrict__ xT) {
    int yy = blockIdx.x;        // 0..65
    int b  = blockIdx.y;
    int yv = yy - 1;
    for (int i = threadIdx.x; i < 68 * 12; i += 256) {
        int xx = i % 68, cig = i / 68;
        int xv = xx - 1;
        ushort_t u[8];
        if (yv >= 0 && yv < 64 && xv >= 0 && xv < 64) {
            const float* sp = x + ((size_t)(b * 96 + cig * 8)) * LL + yv * 64 + xv;
#pragma unroll
            for (int j = 0; j < 8; ++j) u[j] = f2bf(sp[j * LL]);
        } else {
#pragma unroll
            for (int j = 0; j < 8; ++j) u[j] = 0;
        }
        uint4 pk;
        pk.x = u[0] | ((uint_t)u[1] << 16); pk.y = u[2] | ((uint_t)u[3] << 16);
        pk.z = u[4] | ((uint_t)u[5] << 16); pk.w = u[6] | ((uint_t)u[7] << 16);
        *(uint4*)(xT + (((size_t)b * 66 + yy) * 68 + xx) * 96 + cig * 8) = pk;
    }
}

// ---------------- Kernel 2b: implicit-GEMM 3x3 conv via MFMA bf16 -> seqT[b][l][c] bf16
__global__ __launch_bounds__(384, 2) void k_conv_mfma(const ushort_t* __restrict__ xT,
                                                      const ushort_t* __restrict__ Wbf,
                                                      ushort_t* __restrict__ seqT) {
    int tid = threadIdx.x;
    int w = tid >> 6, l = tid & 63;
    int n = l & 15, g = l >> 4;
    int blk = blockIdx.x;
    int b = blk >> 7, rem = blk & 127;
    int y = rem >> 1, half = rem & 1;
    int x0 = (half * 2 + (w & 1)) * 16;
    int co0 = (w >> 1) * 32;
    v4f acc0 = {0.f, 0.f, 0.f, 0.f};
    v4f acc1 = {0.f, 0.f, 0.f, 0.f};
    const ushort_t* xb = xT + (((size_t)b * 66 + y) * 68 + x0 + n) * 96 + g * 8;
    const ushort_t* aw = Wbf + ((size_t)co0 + n) * 96 + g * 8;
#pragma unroll
    for (int tap = 0; tap < 9; ++tap) {
        int dy = tap / 3, dx = tap % 3;
        const ushort_t* bp = xb + (dy * 68 + dx) * 96;
        const ushort_t* ap = aw + (size_t)tap * 96 * 96;
#pragma unroll
        for (int kk = 0; kk < 3; ++kk) {
            v8s bf = *(const v8s*)(bp + kk * 32);
            v8s a0 = *(const v8s*)(ap + kk * 32);
            v8s a1 = *(const v8s*)(ap + 16 * 96 + kk * 32);
            acc0 = __builtin_amdgcn_mfma_f32_16x16x32_bf16(a0, bf, acc0, 0, 0, 0);
            acc1 = __builtin_amdgcn_mfma_f32_16x16x32_bf16(a1, bf, acc1, 0, 0, 0);
        }
    }
    size_t sb = ((size_t)b * 4096 + y * 64 + x0 + n) * 96;
    ushort4 p0, p1;
    p0.x = f2bf(acc0[0]); p0.y = f2bf(acc0[1]); p0.z = f2bf(acc0[2]); p0.w = f2bf(acc0[3]);
    p1.x = f2bf(acc1[0]); p1.y = f2bf(acc1[1]); p1.z = f2bf(acc1[2]); p1.w = f2bf(acc1[3]);
    *(ushort4*)(seqT + sb + co0 + g * 4) = p0;
    *(ushort4*)(seqT + sb + co0 + 16 + g * 4) = p1;
}

// ---------------- Kernel 3: in_proj via MFMA -> xz[b][e][l] f32
__global__ __launch_bounds__(256, 3) void k_inproj(const ushort_t* __restrict__ seqT,
                                                   const ushort_t* __restrict__ Wibf,
                                                   float* __restrict__ xz) {
    int tid = threadIdx.x;
    int w = tid >> 6, l = tid & 63;
    int n = l & 15, g = l >> 4;
    int blk = blockIdx.x;
    int b = blk >> 8;
    int l0 = (blk & 255) * 16;
    int coh = w * 96;
    v4f acc[6];
#pragma unroll
    for (int mt = 0; mt < 6; ++mt) acc[mt] = (v4f){0.f, 0.f, 0.f, 0.f};
    const ushort_t* bp = seqT + ((size_t)b * 4096 + l0 + n) * 96 + g * 8;
    const ushort_t* ap = Wibf + ((size_t)coh + n) * 96 + g * 8;
#pragma unroll
    for (int kk = 0; kk < 3; ++kk) {
        v8s bf = *(const v8s*)(bp + kk * 32);
#pragma unroll
        for (int mt = 0; mt < 6; ++mt) {
            v8s af = *(const v8s*)(ap + mt * 16 * 96 + kk * 32);
            acc[mt] = __builtin_amdgcn_mfma_f32_16x16x32_bf16(af, bf, acc[mt], 0, 0, 0);
        }
    }
    float* ob = xz + (size_t)b * 384 * LL + l0 + n;
#pragma unroll
    for (int mt = 0; mt < 6; ++mt) {
        int e = coh + mt * 16 + g * 4;
#pragma unroll
        for (int r = 0; r < 4; ++r)
            ob[(size_t)(e + r) * LL] = acc[mt][r];
    }
}

// ---------------- Kernel 4: causal depthwise conv1d (k=4) + SiLU -> xc f32 + xcT bf16
__global__ __launch_bounds__(256) void k_conv1d(const float* __restrict__ xz,
                                                const float* __restrict__ w,
                                                const float* __restrict__ bias,
                                                float* __restrict__ xc,
                                                ushort_t* __restrict__ xcT) {
    int tid = blockIdx.x * 256 + threadIdx.x;   // B*192*1024 threads
    int tq = tid & 1023;
    int bd = tid >> 10;
    int d = bd % DIN, b = bd / DIN;
    const float* xin = xz + (size_t)(b * 384 + d) * LL;
    int t0 = tq * 4;
    float4 cur = *(const float4*)(xin + t0);
    float pm3 = 0.f, pm2 = 0.f, pm1 = 0.f;
    if (t0 > 0) {
        float4 prev = *(const float4*)(xin + t0 - 4);
        pm3 = prev.y; pm2 = prev.z; pm1 = prev.w;
    }
    float in[7] = {pm3, pm2, pm1, cur.x, cur.y, cur.z, cur.w};
    float w0 = w[d * 4 + 0], w1 = w[d * 4 + 1], w2 = w[d * 4 + 2], w3 = w[d * 4 + 3];
    float bb = bias[d];
    float o[4];
#pragma unroll
    for (int i = 0; i < 4; ++i) {
        float s = bb + w0 * in[i] + w1 * in[i + 1] + w2 * in[i + 2] + w3 * in[i + 3];
        o[i] = siluf(s);
    }
    float4 ov; ov.x = o[0]; ov.y = o[1]; ov.z = o[2]; ov.w = o[3];
    *(float4*)(xc + (size_t)(b * DIN + d) * LL + t0) = ov;
    ushort_t* xt = xcT + ((size_t)b * 4096 + t0) * DIN + d;
#pragma unroll
    for (int i = 0; i < 4; ++i)
        xt[(size_t)i * DIN] = f2bf(o[i]);
}

// ---------------- Kernel 5: x_proj via MFMA: xdbl[b][l][38] f32, K=192
__global__ __launch_bounds__(256, 4) void k_xprojm(const ushort_t* __restrict__ xcT,
                                                   const ushort_t* __restrict__ Wxbf,
                                                   float* __restrict__ xdbl) {
    int tid = threadIdx.x;
    int w = tid >> 6, l = tid & 63;
    int n = l & 15, g = l >> 4;
    int b = blockIdx.y;
    int l0 = blockIdx.x * 64 + w * 16;
    const ushort_t* bp = xcT + ((size_t)b * 4096 + l0 + n) * 192 + g * 8;
    const ushort_t* ap = Wxbf + (size_t)n * 192 + g * 8;
    v4f acc[3];
#pragma unroll
    for (int m = 0; m < 3; ++m) acc[m] = (v4f){0.f, 0.f, 0.f, 0.f};
#pragma unroll
    for (int kk = 0; kk < 6; ++kk) {
        v8s bf = *(const v8s*)(bp + kk * 32);
#pragma unroll
        for (int m = 0; m < 3; ++m) {
            v8s af = *(const v8s*)(ap + m * 16 * 192 + kk * 32);
            acc[m] = __builtin_amdgcn_mfma_f32_16x16x32_bf16(af, bf, acc[m], 0, 0, 0);
        }
    }
    float* orow = xdbl + ((size_t)b * 4096 + l0 + n) * XE;
#pragma unroll
    for (int m = 0; m < 3; ++m)
#pragma unroll
        for (int r = 0; r < 4; ++r) {
            int e = m * 16 + g * 4 + r;
            if (e < XE) orow[e] = acc[m][r];
        }
}

// ---------------- Kernel 6: dt_proj + softplus -> delta (B,192,L)
__global__ __launch_bounds__(256) void k_dtproj(const float* __restrict__ xdbl,
                                                const float* __restrict__ dtw,
                                                const float* __restrict__ dtb,
                                                float* __restrict__ delta) {
    int tx = threadIdx.x, ty = threadIdx.y;   // (64,4)
    int b = blockIdx.y;
    int l = blockIdx.x * 64 + tx;
    int d0 = blockIdx.z * 48 + ty * 12;
    const float* dtr = xdbl + ((size_t)b * LL + l) * XE;
    float r0 = dtr[0], r1 = dtr[1], r2 = dtr[2], r3 = dtr[3], r4 = dtr[4], r5 = dtr[5];
#pragma unroll
    for (int j = 0; j < 12; ++j) {
        int dd = d0 + j;
        const float* wr2 = dtw + dd * 6;
        float s = dtb[dd] + wr2[0] * r0 + wr2[1] * r1 + wr2[2] * r2
                          + wr2[3] * r3 + wr2[4] * r4 + wr2[5] * r5;
        float e = fexp2(s * 1.44269504f);
        float sp = 0.69314718f * flog2(1.f + e);
        delta[((size_t)b * DIN + dd) * LL + l] = sp;
    }
}

// ---------------- Kernel 7: chunked selective scan + gate -> ygT bf16 (aliased on xz)
#define SC_STEP(DU, UU, BB0, BB1, BB2, BB3)                              \
    {                                                                    \
        float a0 = fexp2((DU).x * A2);                                   \
        float a1 = fexp2((DU).y * A2);                                   \
        float a2 = fexp2((DU).z * A2);                                   \
        float a3 = fexp2((DU).w * A2);                                   \
        h = fmaf(a0, h, (DU).x * (UU).x * (BB0));                        \
        h = fmaf(a1, h, (DU).y * (UU).y * (BB1));                        \
        h = fmaf(a2, h, (DU).z * (UU).z * (BB2));                        \
        h = fmaf(a3, h, (DU).w * (UU).w * (BB3));                        \
        aP *= (a0 * a1) * (a2 * a3);                                     \
    }

#define SC_PSTEP(S, DU, UU, BB0, BB1, BB2, BB3, CC0, CC1, CC2, CC3, ZZ)  \
    {                                                                    \
        float a0 = fexp2((DU).x * A2);                                   \
        float a1 = fexp2((DU).y * A2);                                   \
        float a2 = fexp2((DU).z * A2);                                   \
        float a3 = fexp2((DU).w * A2);                                   \
        h = fmaf(a0, h, (DU).x * (UU).x * (BB0)); float p0 = h * (CC0);  \
        h = fmaf(a1, h, (DU).y * (UU).y * (BB1)); float p1 = h * (CC1);  \
        h = fmaf(a2, h, (DU).z * (UU).z * (BB2)); float p2 = h * (CC2);  \
        h = fmaf(a3, h, (DU).w * (UU).w * (BB3)); float p3 = h * (CC3);  \
        p0 += __shfl_xor(p0, 1); p0 += __shfl_xor(p0, 2);                \
        p0 += __shfl_xor(p0, 4); p0 += __shfl_xor(p0, 8);                \
        p1 += __shfl_xor(p1, 1); p1 += __shfl_xor(p1, 2);                \
        p1 += __shfl_xor(p1, 4); p1 += __shfl_xor(p1, 8);                \
        p2 += __shfl_xor(p2, 1); p2 += __shfl_xor(p2, 2);                \
        p2 += __shfl_xor(p2, 4); p2 += __shfl_xor(p2, 8);                \
        p3 += __shfl_xor(p3, 1); p3 += __shfl_xor(p3, 2);                \
        p3 += __shfl_xor(p3, 4); p3 += __shfl_xor(p3, 8);                \
        float y0 = fmaf(Dd, (UU).x, p0) * siluf((ZZ).x);                 \
        float y1 = fmaf(Dd, (UU).y, p1) * siluf((ZZ).y);                 \
        float y2 = fmaf(Dd, (UU).z, p2) * siluf((ZZ).z);                 \
        float y3 = fmaf(Dd, (UU).w, p3) * siluf((ZZ).w);                 \
        if (n == 0) {                                                    \
            size_t tb_ = (size_t)(t0 + (S) * 4) * DIN + d;               \
            ygb[tb_]           = f2bf(y0);                               \
            ygb[tb_ + DIN]     = f2bf(y1);                               \
            ygb[tb_ + 2 * DIN] = f2bf(y2);                               \
            ygb[tb_ + 3 * DIN] = f2bf(y3);                               \
        }                                                                \
    }

__global__ __launch_bounds__(512, 6) void k_scan(const float* __restrict__ delta,
                                                 const float* __restrict__ xc,
                                                 const float* __restrict__ xdbl,
                                                 const float* __restrict__ A_log,
                                                 const float* __restrict__ Dp,
                                                 float* __restrict__ xz) {
    __shared__ float s_d[32 * 132];       // chunk c at c*132 (+4 pad)
    __shared__ float s_u[32 * 132];
    __shared__ float s_a[32][17];
    __shared__ float s_h[32][17];
    int tid = threadIdx.x;
    int n = tid & 15, cg = tid >> 4;      // 32 chunks x 16 states
    int bd = blockIdx.x;
    int d = bd % DIN, b = bd / DIN;
    const float* drow = delta + (size_t)(b * DIN + d) * LL;
    const float* urow = xc    + (size_t)(b * DIN + d) * LL;
    const float* zrow = xz    + (size_t)(b * 384 + DIN + d) * LL;
    ushort_t* ygb     = (ushort_t*)(xz + (size_t)b * 384 * LL);
    const float* xd   = xdbl  + (size_t)b * LL * XE;
    float A2 = -__expf(A_log[d * NST + n]) * 1.44269504f;   // for fexp2
    float Dd = Dp[d];

    {
        int t8 = tid * 8;
        int li = ((t8 >> 7) * 132) + (t8 & 127);
        *(float4*)&s_d[li]     = *(const float4*)(drow + t8);
        *(float4*)&s_d[li + 4] = *(const float4*)(drow + t8 + 4);
        *(float4*)&s_u[li]     = *(const float4*)(urow + t8);
        *(float4*)&s_u[li + 4] = *(const float4*)(urow + t8 + 4);
    }
    __syncthreads();

    const float* xB = xd + 6 + n;
    const float* xC = xd + 22 + n;
    int t0 = cg * 128;
    int lb = cg * 132;

    // ---- phase 1
    float h = 0.f, aP = 1.f;
    float4 du_c = *(float4*)&s_d[lb];
    float4 u_c  = *(float4*)&s_u[lb];
    int tb = t0 * XE;
    float B0 = xB[tb], B1 = xB[tb + XE], B2 = xB[tb + 2 * XE], B3 = xB[tb + 3 * XE];
    for (int s = 0; s < 31; ++s) {
        int ln = lb + s * 4 + 4;
        int tn = (t0 + s * 4 + 4) * XE;
        float4 du_n = *(float4*)&s_d[ln];
        float4 u_n  = *(float4*)&s_u[ln];
        float Bn0 = xB[tn], Bn1 = xB[tn + XE], Bn2 = xB[tn + 2 * XE], Bn3 = xB[tn + 3 * XE];
        SC_STEP(du_c, u_c, B0, B1, B2, B3);
        du_c = du_n; u_c = u_n; B0 = Bn0; B1 = Bn1; B2 = Bn2; B3 = Bn3;
    }
    SC_STEP(du_c, u_c, B0, B1, B2, B3);
    s_a[cg][n] = aP;
    s_h[cg][n] = h;
    __syncthreads();

    // ---- phase 2: Kogge-Stone scan of 32 chunk aggregates (per n)
    {
        int l = tid & 63, w = tid >> 6;
        int c = l & 31, nn = (w << 1) | (l >> 5);
        float a  = s_a[c][nn];
        float hh = s_h[c][nn];
#pragma unroll
        for (int st = 1; st < 32; st <<= 1) {
            float ap = __shfl_up(a, st, 32);
            float hp = __shfl_up(hh, st, 32);
            bool ok = (c >= st);
            hh = ok ? fmaf(a, hp, hh) : hh;
            a  = ok ? a * ap : a;
        }
        float h0 = __shfl_up(hh, 1, 32);
        if (c == 0) h0 = 0.f;
        s_a[c][nn] = h0;
    }
    __syncthreads();

    // ---- phase 3
    h = s_a[cg][n];
    du_c = *(float4*)&s_d[lb];
    u_c  = *(float4*)&s_u[lb];
    B0 = xB[tb]; B1 = xB[tb + XE]; B2 = xB[tb + 2 * XE]; B3 = xB[tb + 3 * XE];
    float C0 = xC[tb], C1 = xC[tb + XE], C2 = xC[tb + 2 * XE], C3 = xC[tb + 3 * XE];
    float4 z_c = *(const float4*)(zrow + t0);
    for (int s = 0; s < 31; ++s) {
        int ln = lb + s * 4 + 4;
        int tn = (t0 + s * 4 + 4) * XE;
        float4 du_n = *(float4*)&s_d[ln];
        float4 u_n  = *(float4*)&s_u[ln];
        float Bn0 = xB[tn], Bn1 = xB[tn + XE], Bn2 = xB[tn + 2 * XE], Bn3 = xB[tn + 3 * XE];
        float Cn0 = xC[tn], Cn1 = xC[tn + XE], Cn2 = xC[tn + 2 * XE], Cn3 = xC[tn + 3 * XE];
        float4 z_n = *(const float4*)(zrow + t0 + s * 4 + 4);
        SC_PSTEP(s, du_c, u_c, B0, B1, B2, B3, C0, C1, C2, C3, z_c);
        du_c = du_n; u_c = u_n; z_c = z_n;
        B0 = Bn0; B1 = Bn1; B2 = Bn2; B3 = Bn3;
        C0 = Cn0; C1 = Cn1; C2 = Cn2; C3 = Cn3;
    }
    SC_PSTEP(31, du_c, u_c, B0, B1, B2, B3, C0, C1, C2, C3, z_c);
}

// ---------------- Kernel 8: out_proj via MFMA: out[b][c][l] f32 = W[c][d] * ygT[l][d]
// grid (64, 4): each block covers 64 l (4 tiles of 16 via w>>1) x 96 c (2 halves via w&1)
__global__ __launch_bounds__(512, 2) void k_outproj(const float* __restrict__ xzBase,
                                                    const ushort_t* __restrict__ Wobf,
                                                    float* __restrict__ out) {
    int tid = threadIdx.x;
    int w = tid >> 6, l = tid & 63;
    int n = l & 15, g = l >> 4;
    int b = blockIdx.y;
    int l0 = blockIdx.x * 64 + (w >> 1) * 16;
    int c0 = (w & 1) * 48;
    const ushort_t* ygb = (const ushort_t*)(xzBase + (size_t)b * 384 * LL);
    const ushort_t* bp = ygb + ((size_t)l0 + n) * 192 + g * 8;
    const ushort_t* ap = Wobf + ((size_t)c0 + n) * 192 + g * 8;
    v4f acc[3];
#pragma unroll
    for (int m = 0; m < 3; ++m) acc[m] = (v4f){0.f, 0.f, 0.f, 0.f};
#pragma unroll
    for (int kk = 0; kk < 6; ++kk) {
        v8s bf = *(const v8s*)(bp + kk * 32);
#pragma unroll
        for (int m = 0; m < 3; ++m) {
            v8s af = *(const v8s*)(ap + m * 16 * 192 + kk * 32);
            acc[m] = __builtin_amdgcn_mfma_f32_16x16x32_bf16(af, bf, acc[m], 0, 0, 0);
        }
    }
    float* ob = out + (size_t)b * 96 * LL + l0 + n;
#pragma unroll
    for (int m = 0; m < 3; ++m)
#pragma unroll
        for (int r = 0; r < 4; ++r)
            ob[(size_t)(c0 + m * 16 + g * 4 + r) * LL] = acc[m][r];
}

extern "C" void kernel_launch(void* const* d_in, const int* in_sizes, int n_in,
                              void* d_out, int out_size, void* d_ws, size_t ws_size,
                              hipStream_t stream) {
    const float* x         = (const float*)d_in[0];
    const float* proj_w    = (const float*)d_in[1];
    const float* dconv_w   = (const float*)d_in[2];
    const float* in_proj_w = (const float*)d_in[3];
    const float* conv1d_w  = (const float*)d_in[4];
    const float* conv1d_b  = (const float*)d_in[5];
    const float* x_proj_w  = (const float*)d_in[6];
    const float* dt_proj_w = (const float*)d_in[7];
    const float* dt_proj_b = (const float*)d_in[8];
    const float* A_log     = (const float*)d_in[9];
    const float* Dp        = (const float*)d_in[10];
    const float* out_proj_w= (const float*)d_in[11];
    float* out = (float*)d_out;
    float* ws  = (float*)d_ws;

    // carve (float units)
    ushort_t* Wbf  = (ushort_t*)ws;                      // 82,944 sh -> 41,472 fl
    ushort_t* Wibf = (ushort_t*)(ws + 41472);            // 36,864 sh -> 18,432 fl
    ushort_t* Wobf = (ushort_t*)(ws + 59904);            // 18,432 sh ->  9,216 fl
    ushort_t* Wxbf = (ushort_t*)(ws + 69120);            //  9,216 sh ->  4,608 fl
    ushort_t* xT   = (ushort_t*)(ws + 73728);            // 1,723,392 sh -> 861,696 fl
    ushort_t* seqT = (ushort_t*)(ws + 935424);           // 1,572,864 sh -> 786,432 fl
    float* xz   = ws + 1721856;                          // 4*384*4096 = 6,291,456
    float* xc   = xz + 6291456;                          // 3,145,728
    float* xdbl = xc + 3145728;                          //   622,592
    float* delta= xdbl + 622592;                         // 3,145,728
    ushort_t* xcT = (ushort_t*)delta;                    // alias: dead once delta written
    // ygT aliases xz lower half per-batch (xin dead after conv1d)

    k_merge_w<<<dim3(324), dim3(256), 0, stream>>>(proj_w, dconv_w, Wbf);
    k_cvt_all<<<dim3(252), dim3(256), 0, stream>>>(in_proj_w, out_proj_w, x_proj_w,
                                                   Wibf, Wobf, Wxbf);
    k_xpad<<<dim3(66, 4), dim3(256), 0, stream>>>(x, xT);
    k_conv_mfma<<<dim3(512), dim3(384), 0, stream>>>(xT, Wbf, seqT);
    k_inproj<<<dim3(1024), dim3(256), 0, stream>>>(seqT, Wibf, xz);
    k_conv1d<<<dim3(3072), dim3(256), 0, stream>>>(xz, conv1d_w, conv1d_b, xc, xcT);
    k_xprojm<<<dim3(64, 4), dim3(256), 0, stream>>>(xcT, Wxbf, xdbl);
    k_dtproj<<<dim3(64, 4, 4), dim3(64, 4), 0, stream>>>(xdbl, dt_proj_w, dt_proj_b, delta);
    k_scan<<<dim3(768), dim3(512), 0, stream>>>(delta, xc, xdbl, A_log, Dp, xz);
    k_outproj<<<dim3(64, 4), dim3(512), 0, stream>>>(xz, Wobf, out);
}